// Round 2
// baseline (340.047 us; speedup 1.0000x reference)
//
#include <hip/hip_runtime.h>
#include <hip/hip_bf16.h>

// Problem: B=512, S=16384, C=3. logits f32 [B,S,3], labels i32 [B,S].
// out = mean over valid of ( -w[lab]*logp[lab]  - 2.0*(true_sw & pred_near)
//                            + 1.5*(pred_sw & ~true_near & has_true_row & valid) )
// window radius TOL=5, per-row (edge-clipped).

#define TOL 5
#define BLOCK 256
#define CHUNK 1024   // positions per block in K1

typedef unsigned long long u64;

// ---------------- K1: streaming pass ----------------
// Coalesced LDS-staged load; per-position CE + switch bits; ballot -> u64 masks.
__global__ __launch_bounds__(BLOCK) void k1_stream(
    const float* __restrict__ logits, const int* __restrict__ labels,
    u64* __restrict__ pmask, u64* __restrict__ tmask, u64* __restrict__ vmask,
    double* __restrict__ base_sum, u64* __restrict__ valid_cnt)
{
    __shared__ float lds_l[CHUNK * 3];   // 12 KB
    __shared__ int   lds_lab[CHUNK];     // 4 KB
    __shared__ float wb[BLOCK / 64];
    __shared__ int   wv[BLOCK / 64];

    const int tid = threadIdx.x;
    const long long chunk = blockIdx.x;

    // stage logits: 3072 floats = 768 float4, 3 per thread, fully coalesced
    const float4* gl4 = (const float4*)logits + chunk * (CHUNK * 3 / 4);
    float4* ll4 = (float4*)lds_l;
#pragma unroll
    for (int k = 0; k < 3; ++k) ll4[tid + k * BLOCK] = gl4[tid + k * BLOCK];
    // stage labels: 1024 ints = 256 int4, coalesced
    const int4* gi4 = (const int4*)labels + chunk * (CHUNK / 4);
    ((int4*)lds_lab)[tid] = gi4[tid];
    __syncthreads();

    float bsum = 0.f;
    int   vcnt = 0;
    const int wave = tid >> 6;
    const u64 base_group = (u64)chunk * (CHUNK / 64);

#pragma unroll
    for (int q = 0; q < CHUNK / BLOCK; ++q) {
        const int pos = q * BLOCK + tid;
        const float l0 = lds_l[3 * pos + 0];
        const float l1 = lds_l[3 * pos + 1];
        const float l2 = lds_l[3 * pos + 2];
        const int lab = lds_lab[pos];

        const bool valid = (lab != -100);
        const int ls = valid ? lab : 0;

        // log-softmax picked value
        const float mx = fmaxf(l0, fmaxf(l1, l2));
        const float se = __expf(l0 - mx) + __expf(l1 - mx) + __expf(l2 - mx);
        const float lse = mx + __logf(se);
        const float lpick = (ls == 0 ? l0 : (ls == 1 ? l1 : l2)) - lse;
        const float w = (ls == 0) ? 0.1f : 5.0f;
        bsum += valid ? (-w * lpick) : 0.f;
        vcnt += valid ? 1 : 0;

        // argmax (first-occurrence): pred==0 iff l0 >= l1 && l0 >= l2
        const bool psw = fmaxf(l1, l2) > l0;
        const bool tsw = (lab >= 1);   // -100 < 1 -> false

        const u64 pm = __ballot(psw);
        const u64 tm = __ballot(tsw);
        const u64 vm = __ballot(valid);
        if ((tid & 63) == 0) {
            const u64 g = base_group + (u64)(q * (BLOCK / 64) + wave);
            pmask[g] = pm; tmask[g] = tm; vmask[g] = vm;
        }
    }

    // block reduce bsum / vcnt
#pragma unroll
    for (int off = 32; off; off >>= 1) {
        bsum += __shfl_down(bsum, off);
        vcnt += __shfl_down(vcnt, off);
    }
    if ((tid & 63) == 0) { wb[wave] = bsum; wv[wave] = vcnt; }
    __syncthreads();
    if (tid == 0) {
        double s = 0.0; int c = 0;
#pragma unroll
        for (int i = 0; i < BLOCK / 64; ++i) { s += (double)wb[i]; c += wv[i]; }
        atomicAdd(base_sum, s);
        atomicAdd(valid_cnt, (u64)c);
    }
}

// ---------------- K2: per-row window + counts ----------------
// One block per row, one thread per 64-position group (S/64 == 256 == BLOCK).
__global__ __launch_bounds__(BLOCK) void k2_window(
    const u64* __restrict__ pmask, const u64* __restrict__ tmask,
    const u64* __restrict__ vmask, double* __restrict__ adj)
{
    const int row = blockIdx.x;
    const int t = threadIdx.x;
    const int GPR = BLOCK;               // groups per row
    const long long base = (long long)row * GPR + t;

    const u64 pm = pmask[base];
    const u64 tm = tmask[base];
    const u64 vm = vmask[base];
    const u64 pp = (t > 0)       ? pmask[base - 1] : 0ULL;
    const u64 pn = (t < GPR - 1) ? pmask[base + 1] : 0ULL;
    const u64 tp = (t > 0)       ? tmask[base - 1] : 0ULL;
    const u64 tn = (t < GPR - 1) ? tmask[base + 1] : 0ULL;

    u64 pnear = pm, tnear = tm;
#pragma unroll
    for (int k = 1; k <= TOL; ++k) {
        pnear |= (pm << k) | (pm >> k) | (pp >> (64 - k)) | (pn << (64 - k));
        tnear |= (tm << k) | (tm >> k) | (tp >> (64 - k)) | (tn << (64 - k));
    }

    int reward  = __popcll(tm & pnear);            // true_sw implies valid
    int penalty = __popcll(pm & ~tnear & vm);      // gated by valid mask
    int ht = (tm != 0ULL) ? 1 : 0;

#pragma unroll
    for (int off = 32; off; off >>= 1) {
        reward  += __shfl_down(reward, off);
        penalty += __shfl_down(penalty, off);
        ht      |= __shfl_down(ht, off);
    }
    __shared__ int rs[BLOCK / 64], ps[BLOCK / 64], hs[BLOCK / 64];
    const int wave = t >> 6;
    if ((t & 63) == 0) { rs[wave] = reward; ps[wave] = penalty; hs[wave] = ht; }
    __syncthreads();
    if (t == 0) {
        int R = 0, P = 0, H = 0;
#pragma unroll
        for (int i = 0; i < BLOCK / 64; ++i) { R += rs[i]; P += ps[i]; H |= hs[i]; }
        const double a = -2.0 * (double)R + (H ? 1.5 * (double)P : 0.0);
        atomicAdd(adj, a);
    }
}

// ---------------- K3: final divide ----------------
__global__ void k3_final(const double* __restrict__ base_sum,
                         const double* __restrict__ adj,
                         const u64* __restrict__ valid_cnt,
                         float* __restrict__ out)
{
    out[0] = (float)((base_sum[0] + adj[0]) / (double)valid_cnt[0]);
}

extern "C" void kernel_launch(void* const* d_in, const int* in_sizes, int n_in,
                              void* d_out, int out_size, void* d_ws, size_t ws_size,
                              hipStream_t stream) {
    const float* logits = (const float*)d_in[0];
    const int*   labels = (const int*)d_in[1];
    float* out = (float*)d_out;

    const long long BS = in_sizes[1];        // B*S = 8388608
    const long long NGROUP = BS / 64;        // 131072

    char* ws = (char*)d_ws;
    double* base_sum = (double*)ws;                      // 8 B
    double* adj      = (double*)(ws + 8);                // 8 B
    u64*    vcnt     = (u64*)(ws + 16);                  // 8 B
    u64* pmask = (u64*)(ws + 64);
    u64* tmask = pmask + NGROUP;
    u64* vmask = tmask + NGROUP;

    hipMemsetAsync(ws, 0, 64, stream);

    const int B = 512;                       // S = 16384 -> 256 groups/row
    const long long nchunk = BS / CHUNK;     // 8192

    k1_stream<<<(dim3)(unsigned)nchunk, BLOCK, 0, stream>>>(
        logits, labels, pmask, tmask, vmask, base_sum, vcnt);
    k2_window<<<B, BLOCK, 0, stream>>>(pmask, tmask, vmask, adj);
    k3_final<<<1, 1, 0, stream>>>(base_sum, adj, vcnt, out);
}

// Round 6
// 182.169 us; speedup vs baseline: 1.8667x; 1.8667x over previous
//
#include <hip/hip_runtime.h>
#include <hip/hip_bf16.h>

// B=512, S=16384, C=3. logits f32 [B,S,3], labels i32 [B,S].
// out = mean over valid of ( -w[lab]*logp[lab] - 2.0*(true_sw & pred_near)
//                            + 1.5*(pred_sw & ~true_near & has_true_row & valid) )
// window radius TOL=5, per-row (edge-clipped).
// NO global atomics anywhere: fp64 atomicAdd = CAS loop on gfx950 (default flags),
// 16K same-line contenders cost ~200us (round-2 post-mortem). Per-block partials instead.

#define TOL 5
#define BLOCK 256
#define CHUNK 1024   // positions per block in K1

typedef unsigned long long u64;

// ---------------- K1: streaming pass ----------------
__global__ __launch_bounds__(BLOCK) void k1_stream(
    const float* __restrict__ logits, const int* __restrict__ labels,
    u64* __restrict__ pmask, u64* __restrict__ tmask, u64* __restrict__ vmask,
    double* __restrict__ pbsum, int* __restrict__ pvcnt)
{
    __shared__ float lds_l[CHUNK * 3];   // 12 KB
    __shared__ int   lds_lab[CHUNK];     // 4 KB
    __shared__ float wb[BLOCK / 64];
    __shared__ int   wv[BLOCK / 64];

    const int tid = threadIdx.x;
    const long long chunk = blockIdx.x;

    // stage logits: 3072 floats = 768 float4, 3 per thread, fully coalesced
    const float4* gl4 = (const float4*)logits + chunk * (CHUNK * 3 / 4);
    float4* ll4 = (float4*)lds_l;
#pragma unroll
    for (int k = 0; k < 3; ++k) ll4[tid + k * BLOCK] = gl4[tid + k * BLOCK];
    const int4* gi4 = (const int4*)labels + chunk * (CHUNK / 4);
    ((int4*)lds_lab)[tid] = gi4[tid];
    __syncthreads();

    float bsum = 0.f;
    int   vcnt = 0;
    const int wave = tid >> 6;
    const u64 base_group = (u64)chunk * (CHUNK / 64);

#pragma unroll
    for (int q = 0; q < CHUNK / BLOCK; ++q) {
        const int pos = q * BLOCK + tid;
        const float l0 = lds_l[3 * pos + 0];   // stride-3 LDS: bank permutation, 2-way only (free)
        const float l1 = lds_l[3 * pos + 1];
        const float l2 = lds_l[3 * pos + 2];
        const int lab = lds_lab[pos];

        const bool valid = (lab != -100);
        const int ls = valid ? lab : 0;

        const float mx = fmaxf(l0, fmaxf(l1, l2));
        const float se = __expf(l0 - mx) + __expf(l1 - mx) + __expf(l2 - mx);
        const float lse = mx + __logf(se);
        const float lpick = (ls == 0 ? l0 : (ls == 1 ? l1 : l2)) - lse;
        const float w = (ls == 0) ? 0.1f : 5.0f;
        bsum += valid ? (-w * lpick) : 0.f;
        vcnt += valid ? 1 : 0;

        // argmax first-occurrence: pred>=1 iff max(l1,l2) > l0
        const bool psw = fmaxf(l1, l2) > l0;
        const bool tsw = (lab >= 1);   // -100 excluded

        const u64 pm = __ballot(psw);
        const u64 tm = __ballot(tsw);
        const u64 vm = __ballot(valid);
        if ((tid & 63) == 0) {
            const u64 g = base_group + (u64)(q * (BLOCK / 64) + wave);
            pmask[g] = pm; tmask[g] = tm; vmask[g] = vm;
        }
    }

    // block reduce bsum / vcnt  -> per-block partial (no atomics)
#pragma unroll
    for (int off = 32; off; off >>= 1) {
        bsum += __shfl_down(bsum, off);
        vcnt += __shfl_down(vcnt, off);
    }
    if ((tid & 63) == 0) { wb[wave] = bsum; wv[wave] = vcnt; }
    __syncthreads();
    if (tid == 0) {
        double s = 0.0; int c = 0;
#pragma unroll
        for (int i = 0; i < BLOCK / 64; ++i) { s += (double)wb[i]; c += wv[i]; }
        pbsum[chunk] = s;
        pvcnt[chunk] = c;
    }
}

// ---------------- K2: per-row window + counts ----------------
// One block per row, one thread per 64-position group (S/64 == 256 == BLOCK).
__global__ __launch_bounds__(BLOCK) void k2_window(
    const u64* __restrict__ pmask, const u64* __restrict__ tmask,
    const u64* __restrict__ vmask, float* __restrict__ adj_row)
{
    const int row = blockIdx.x;
    const int t = threadIdx.x;
    const int GPR = BLOCK;               // groups per row
    const long long base = (long long)row * GPR + t;

    const u64 pm = pmask[base];
    const u64 tm = tmask[base];
    const u64 vm = vmask[base];
    const u64 pp = (t > 0)       ? pmask[base - 1] : 0ULL;
    const u64 pn = (t < GPR - 1) ? pmask[base + 1] : 0ULL;
    const u64 tp = (t > 0)       ? tmask[base - 1] : 0ULL;
    const u64 tn = (t < GPR - 1) ? tmask[base + 1] : 0ULL;

    u64 pnear = pm, tnear = tm;
#pragma unroll
    for (int k = 1; k <= TOL; ++k) {
        pnear |= (pm << k) | (pm >> k) | (pp >> (64 - k)) | (pn << (64 - k));
        tnear |= (tm << k) | (tm >> k) | (tp >> (64 - k)) | (tn << (64 - k));
    }

    int reward  = __popcll(tm & pnear);            // true_sw implies valid
    int penalty = __popcll(pm & ~tnear & vm);      // gated by valid mask
    int ht = (tm != 0ULL) ? 1 : 0;

#pragma unroll
    for (int off = 32; off; off >>= 1) {
        reward  += __shfl_down(reward, off);
        penalty += __shfl_down(penalty, off);
        ht      |= __shfl_down(ht, off);
    }
    __shared__ int rs[BLOCK / 64], ps[BLOCK / 64], hs[BLOCK / 64];
    const int wave = t >> 6;
    if ((t & 63) == 0) { rs[wave] = reward; ps[wave] = penalty; hs[wave] = ht; }
    __syncthreads();
    if (t == 0) {
        int R = 0, P = 0, H = 0;
#pragma unroll
        for (int i = 0; i < BLOCK / 64; ++i) { R += rs[i]; P += ps[i]; H |= hs[i]; }
        adj_row[row] = -2.0f * (float)R + (H ? 1.5f * (float)P : 0.0f);  // exact ints, fits f32
    }
}

// ---------------- K3: final reduce + divide (one block) ----------------
__global__ __launch_bounds__(BLOCK) void k3_reduce(
    const double* __restrict__ pbsum, const int* __restrict__ pvcnt, int nblocks,
    const float* __restrict__ adj_row, int nrows,
    float* __restrict__ out)
{
    const int t = threadIdx.x;
    double s = 0.0, a = 0.0;
    long long c = 0;
    for (int i = t; i < nblocks; i += BLOCK) { s += pbsum[i]; c += (long long)pvcnt[i]; }
    for (int i = t; i < nrows; i += BLOCK) a += (double)adj_row[i];

#pragma unroll
    for (int off = 32; off; off >>= 1) {
        s += __shfl_down(s, off);
        a += __shfl_down(a, off);
        c += __shfl_down(c, off);
    }
    __shared__ double ss[BLOCK / 64], as[BLOCK / 64];
    __shared__ long long cs[BLOCK / 64];
    const int wave = t >> 6;
    if ((t & 63) == 0) { ss[wave] = s; as[wave] = a; cs[wave] = c; }
    __syncthreads();
    if (t == 0) {
        double S = 0.0, A = 0.0; long long C = 0;
#pragma unroll
        for (int i = 0; i < BLOCK / 64; ++i) { S += ss[i]; A += as[i]; C += cs[i]; }
        out[0] = (float)((S + A) / (double)C);
    }
}

extern "C" void kernel_launch(void* const* d_in, const int* in_sizes, int n_in,
                              void* d_out, int out_size, void* d_ws, size_t ws_size,
                              hipStream_t stream) {
    const float* logits = (const float*)d_in[0];
    const int*   labels = (const int*)d_in[1];
    float* out = (float*)d_out;

    const long long BS = in_sizes[1];        // B*S = 8388608
    const long long NGROUP = BS / 64;        // 131072
    const int B = 512;                       // S = 16384 -> 256 groups/row
    const long long nchunk = BS / CHUNK;     // 8192

    char* ws = (char*)d_ws;
    u64* pmask = (u64*)ws;                               // 1 MB
    u64* tmask = pmask + NGROUP;                         // 1 MB
    u64* vmask = tmask + NGROUP;                         // 1 MB
    double* pbsum = (double*)(vmask + NGROUP);           // 64 KB
    int* pvcnt    = (int*)(pbsum + nchunk);              // 32 KB
    float* adjrow = (float*)(pvcnt + nchunk);            // 2 KB

    k1_stream<<<(dim3)(unsigned)nchunk, BLOCK, 0, stream>>>(
        logits, labels, pmask, tmask, vmask, pbsum, pvcnt);
    k2_window<<<B, BLOCK, 0, stream>>>(pmask, tmask, vmask, adjrow);
    k3_reduce<<<1, BLOCK, 0, stream>>>(pbsum, pvcnt, (int)nchunk, adjrow, B, out);
}

// Round 13
// 174.479 us; speedup vs baseline: 1.9489x; 1.0441x over previous
//
#include <hip/hip_runtime.h>
#include <hip/hip_bf16.h>

// B=512, S=16384, C=3. logits f32 [B,S,3], labels i32 [B,S].
// out = mean over valid of ( -w[lab]*logp[lab] - 2.0*(true_sw & pred_near)
//                            + 1.5*(pred_sw & ~true_near & has_true_row & valid) )
// TOL=5 window, per-row edge-clipped.
//
// One block per row: stream row -> CE sum + ballot masks in LDS -> windowed
// popcounts in the same block -> one (f32,i32) partial per row. No global
// atomics (round-2: contended f64 CAS cost ~200us), no mask HBM round-trip,
// final reduce reads only 4KB.

#define TOL 5
#define BLOCK 256
#define SROW 16384
#define GPRW (SROW / 64)       // 256 groups per row == BLOCK
#define CHUNK 1024             // positions staged per iteration
#define NITER (SROW / CHUNK)   // 16

typedef unsigned long long u64;

// ---------------- K1: one block per row ----------------
__global__ __launch_bounds__(BLOCK) void k1_row(
    const float* __restrict__ logits, const int* __restrict__ labels,
    float* __restrict__ row_sum, int* __restrict__ row_cnt)
{
    __shared__ float lds_l[CHUNK * 3];          // 12 KB staging
    __shared__ int   lds_lab[CHUNK];            // 4 KB
    __shared__ u64 pm_s[GPRW], tm_s[GPRW], vm_s[GPRW];  // 6 KB masks
    __shared__ float wb[4];
    __shared__ int wv[4], rs[4], ps[4], hs[4];

    const int tid = threadIdx.x;
    const int wave = tid >> 6;
    const int row = blockIdx.x;
    const long long rowbase = (long long)row * SROW;

    const float4* gl4 = (const float4*)(logits + rowbase * 3);  // 768 float4 per chunk
    const int4*   gi4 = (const int4*)(labels + rowbase);        // 256 int4 per chunk

    // preload chunk 0 into registers (T14: issue early, write late)
    float4 pf0 = gl4[tid], pf1 = gl4[tid + BLOCK], pf2 = gl4[tid + 2 * BLOCK];
    int4   pi  = gi4[tid];

    float bsum = 0.f;
    int   vcnt = 0;

    for (int it = 0; it < NITER; ++it) {
        ((float4*)lds_l)[tid]             = pf0;
        ((float4*)lds_l)[tid + BLOCK]     = pf1;
        ((float4*)lds_l)[tid + 2 * BLOCK] = pf2;
        ((int4*)lds_lab)[tid]             = pi;
        __syncthreads();

        if (it + 1 < NITER) {   // prefetch next chunk; latency hides under compute
            const float4* g = gl4 + (long long)(it + 1) * (CHUNK * 3 / 4);
            pf0 = g[tid]; pf1 = g[tid + BLOCK]; pf2 = g[tid + 2 * BLOCK];
            pi  = gi4[(long long)(it + 1) * (CHUNK / 4) + tid];
        }

#pragma unroll
        for (int q = 0; q < CHUNK / BLOCK; ++q) {
            const int pos = q * BLOCK + tid;
            const float l0 = lds_l[3 * pos + 0];   // stride-3: bank permutation, benign
            const float l1 = lds_l[3 * pos + 1];
            const float l2 = lds_l[3 * pos + 2];
            const int lab = lds_lab[pos];

            const bool valid = (lab != -100);
            const int ls = valid ? lab : 0;

            const float mx = fmaxf(l0, fmaxf(l1, l2));
            const float se = __expf(l0 - mx) + __expf(l1 - mx) + __expf(l2 - mx);
            const float lse = mx + __logf(se);
            const float lpick = (ls == 0 ? l0 : (ls == 1 ? l1 : l2)) - lse;
            const float w = (ls == 0) ? 0.1f : 5.0f;
            bsum += valid ? (-w * lpick) : 0.f;
            vcnt += valid ? 1 : 0;

            // argmax first-occurrence: pred>=1 iff max(l1,l2) > l0
            const bool psw = fmaxf(l1, l2) > l0;
            const bool tsw = (lab >= 1);           // -100 excluded

            const u64 pm = __ballot(psw);
            const u64 tm = __ballot(tsw);
            const u64 vm = __ballot(valid);
            if ((tid & 63) == 0) {
                const int g = it * (CHUNK / 64) + q * (BLOCK / 64) + wave;
                pm_s[g] = pm; tm_s[g] = tm; vm_s[g] = vm;
            }
        }
        __syncthreads();   // masks visible + staging buffer reusable
    }

    // ---------- phase 2: windowed counts, thread t owns group t ----------
    const u64 pm = pm_s[tid], tm = tm_s[tid], vm = vm_s[tid];
    const u64 pp = (tid > 0)        ? pm_s[tid - 1] : 0ULL;
    const u64 pn = (tid < GPRW - 1) ? pm_s[tid + 1] : 0ULL;
    const u64 tp = (tid > 0)        ? tm_s[tid - 1] : 0ULL;
    const u64 tn = (tid < GPRW - 1) ? tm_s[tid + 1] : 0ULL;

    u64 pnear = pm, tnear = tm;
#pragma unroll
    for (int k = 1; k <= TOL; ++k) {
        pnear |= (pm << k) | (pm >> k) | (pp >> (64 - k)) | (pn << (64 - k));
        tnear |= (tm << k) | (tm >> k) | (tp >> (64 - k)) | (tn << (64 - k));
    }

    int reward  = __popcll(tm & pnear);        // true_sw implies valid
    int penalty = __popcll(pm & ~tnear & vm);  // gated by valid
    int ht = (tm != 0ULL) ? 1 : 0;

#pragma unroll
    for (int off = 32; off; off >>= 1) {
        bsum    += __shfl_down(bsum, off);
        vcnt    += __shfl_down(vcnt, off);
        reward  += __shfl_down(reward, off);
        penalty += __shfl_down(penalty, off);
        ht      |= __shfl_down(ht, off);
    }
    if ((tid & 63) == 0) { wb[wave] = bsum; wv[wave] = vcnt; rs[wave] = reward; ps[wave] = penalty; hs[wave] = ht; }
    __syncthreads();
    if (tid == 0) {
        float S = 0.f; int C = 0, R = 0, P = 0, H = 0;
#pragma unroll
        for (int i = 0; i < 4; ++i) { S += wb[i]; C += wv[i]; R += rs[i]; P += ps[i]; H |= hs[i]; }
        row_sum[row] = S - 2.0f * (float)R + (H ? 1.5f * (float)P : 0.0f);
        row_cnt[row] = C;
    }
}

// ---------------- K2: final reduce over 512 rows (4 KB) ----------------
__global__ __launch_bounds__(BLOCK) void k2_final(
    const float* __restrict__ row_sum, const int* __restrict__ row_cnt,
    int nrows, float* __restrict__ out)
{
    const int t = threadIdx.x;
    double s = 0.0;
    long long c = 0;
    for (int i = t; i < nrows; i += BLOCK) { s += (double)row_sum[i]; c += (long long)row_cnt[i]; }

#pragma unroll
    for (int off = 32; off; off >>= 1) {
        s += __shfl_down(s, off);
        c += __shfl_down(c, off);
    }
    __shared__ double ss[4];
    __shared__ long long cs[4];
    const int wave = t >> 6;
    if ((t & 63) == 0) { ss[wave] = s; cs[wave] = c; }
    __syncthreads();
    if (t == 0) {
        double S = 0.0; long long C = 0;
#pragma unroll
        for (int i = 0; i < 4; ++i) { S += ss[i]; C += cs[i]; }
        out[0] = (float)(S / (double)C);
    }
}

extern "C" void kernel_launch(void* const* d_in, const int* in_sizes, int n_in,
                              void* d_out, int out_size, void* d_ws, size_t ws_size,
                              hipStream_t stream) {
    const float* logits = (const float*)d_in[0];
    const int*   labels = (const int*)d_in[1];
    float* out = (float*)d_out;

    const long long BS = in_sizes[1];       // B*S = 8388608
    const int B = (int)(BS / SROW);         // 512 rows

    char* ws = (char*)d_ws;
    float* row_sum = (float*)ws;            // 2 KB
    int*   row_cnt = (int*)(row_sum + B);   // 2 KB

    k1_row<<<B, BLOCK, 0, stream>>>(logits, labels, row_sum, row_cnt);
    k2_final<<<1, BLOCK, 0, stream>>>(row_sum, row_cnt, B, out);
}